// Round 1
// baseline (601.420 us; speedup 1.0000x reference)
//
#include <hip/hip_runtime.h>
#include <hip/hip_bf16.h>
#include <stdint.h>

#define DIN   4096
#define DOUT  4096
#define MROWS 8192   // B*S = 4*2048

typedef __bf16 bf16_t;
typedef __attribute__((ext_vector_type(8))) __bf16 bf16x8;
typedef __attribute__((ext_vector_type(4))) float   f32x4;

__device__ __forceinline__ unsigned short f2bf(float f) {
    union { float f; unsigned u; } v; v.f = f;
    unsigned r = v.u + 0x7FFFu + ((v.u >> 16) & 1u);   // RNE
    return (unsigned short)(r >> 16);
}

// ---------------------------------------------------------------------------
// Kernel 1: Wt[n][k] = bf16( base_T[k][n] + c * (2*mask[k][n] - 1) )
// ---------------------------------------------------------------------------
__global__ __launch_bounds__(256)
void build_wt(const float* __restrict__ baseT,
              const int*   __restrict__ mask,
              const float* __restrict__ coeff,
              unsigned short* __restrict__ Wt) {
    __shared__ float tile[64][68];
    const float c = coeff[0];
    const int t  = threadIdx.x;
    const int n0 = blockIdx.x * 64;
    const int k0 = blockIdx.y * 64;

    const int kr = t >> 4;
    const int nv = (t & 15) * 4;
#pragma unroll
    for (int i = 0; i < 4; ++i) {
        const int kl = i * 16 + kr;
        const size_t idx = (size_t)(k0 + kl) * DOUT + n0 + nv;
        float4 b4 = *(const float4*)(baseT + idx);
        int4   m4 = *(const int4*)(mask + idx);
        float4 v;
        v.x = b4.x + c * (float)(2 * m4.x - 1);
        v.y = b4.y + c * (float)(2 * m4.y - 1);
        v.z = b4.z + c * (float)(2 * m4.z - 1);
        v.w = b4.w + c * (float)(2 * m4.w - 1);
        *(float4*)&tile[kl][nv] = v;
    }
    __syncthreads();

    const int nr = t >> 4;
    const int kv = (t & 15) * 4;
#pragma unroll
    for (int j = 0; j < 4; ++j) {
        const int nl = j * 16 + nr;
        ushort4 o;
        o.x = f2bf(tile[kv + 0][nl]);
        o.y = f2bf(tile[kv + 1][nl]);
        o.z = f2bf(tile[kv + 2][nl]);
        o.w = f2bf(tile[kv + 3][nl]);
        *(ushort4*)(Wt + (size_t)(n0 + nl) * DIN + k0 + kv) = o;
    }
}

// ---------------------------------------------------------------------------
// Kernel 2: x fp32 -> bf16 bits, 16 elem/thread
// ---------------------------------------------------------------------------
__global__ __launch_bounds__(256)
void cvt_x(const float* __restrict__ x, unsigned short* __restrict__ xb) {
    const int i = blockIdx.x * 256 + threadIdx.x;
    const float4* xv = (const float4*)x;
    float4 a = xv[4 * i + 0];
    float4 b = xv[4 * i + 1];
    float4 c = xv[4 * i + 2];
    float4 d = xv[4 * i + 3];
    union { ushort4 s[2]; uint4 u; } p0, p1;
    p0.s[0] = make_ushort4(f2bf(a.x), f2bf(a.y), f2bf(a.z), f2bf(a.w));
    p0.s[1] = make_ushort4(f2bf(b.x), f2bf(b.y), f2bf(b.z), f2bf(b.w));
    p1.s[0] = make_ushort4(f2bf(c.x), f2bf(c.y), f2bf(c.z), f2bf(c.w));
    p1.s[1] = make_ushort4(f2bf(d.x), f2bf(d.y), f2bf(d.z), f2bf(d.w));
    uint4* ov = (uint4*)xb;
    ov[2 * i + 0] = p0.u;
    ov[2 * i + 1] = p1.u;
}

// ---------------------------------------------------------------------------
// Kernel 3: out[m][n] = sum_k X[m][k] * Wt[n][k]   (bf16 in, fp32 out)
// 256x256 tile, BK=64, 8 waves (2Mx4N), 8-phase counted-vmcnt schedule
// (T2+T3+T4+T5 per guide §5). 2 K-tiles per loop iteration, double-buffered
// 128 KiB LDS. vmcnt(4) only at phases 4/8 -> loads stay in flight across
// barriers (no vmcnt(0) drain in the main loop).
// LDS swizzle: phys chunk p at row r holds global chunk p ^ (r&7)
// (pre-swizzled global source; linear global_load_lds dest) -> conflict-free
// ds_read_b128 fragments (2-way = free).
// Stage->phase map (iter i; Ktiles 2i in buf0, 2i+1 in buf1):
//   P1: buf1.B0@(2i+1)  P2: buf1.B1@(2i+1)   [B(buf1) free after P7-prev]
//   P3: buf0.A0@(2i+2)  P4: buf0.A1@(2i+2)   [A(buf0) free after P2]
//   P5: buf0.B0@(2i+2)  P6: buf0.B1@(2i+2)   [B(buf0) free after P3]
//   P7: buf1.A0@(2i+3)  P8: buf1.A1@(2i+3)   [A(buf1) free after P6]
// vmcnt(4)@P4 -> stages through P2 landed (buf1 complete for P5 reads);
// vmcnt(4)@P8 -> stages through P6 landed (buf0 complete for P1' reads).
// ---------------------------------------------------------------------------
#define AS1 __attribute__((address_space(1)))
#define AS3 __attribute__((address_space(3)))
#define GLD16(src, dst) \
    __builtin_amdgcn_global_load_lds((const AS1 void*)(src), (AS3 void*)(dst), 16, 0, 0)
#define SB __builtin_amdgcn_sched_barrier(0)

#define PH_HEAD do { SB; __builtin_amdgcn_s_barrier(); \
    asm volatile("s_waitcnt lgkmcnt(0)" ::: "memory"); SB; \
    __builtin_amdgcn_s_setprio(1); } while (0)
#define PH_TAIL do { __builtin_amdgcn_s_setprio(0); SB; \
    __builtin_amdgcn_s_barrier(); SB; } while (0)
#define PH_TAIL_VM do { __builtin_amdgcn_s_setprio(0); SB; \
    asm volatile("s_waitcnt vmcnt(4)" ::: "memory"); \
    __builtin_amdgcn_s_barrier(); SB; } while (0)

// stage one 128-row half-tile: wave wv instr j covers rows wv*16+j*8..+8,
// lane l -> row +(l>>3), phys chunk l&7 <- global chunk (l&7)^(l>>3)
#define STG_A(b, h, kb) do { \
    GLD16(gA + (size_t)((h) * 128 + 0) * DIN + (kb), &sA[b][(h) * 8192 + wv * 1024 + 0]);   \
    GLD16(gA + (size_t)((h) * 128 + 8) * DIN + (kb), &sA[b][(h) * 8192 + wv * 1024 + 512]); \
} while (0)
#define STG_B(b, h, kb) do { \
    GLD16(gB + (size_t)((h) * 128 + 0) * DIN + (kb), &sB[b][(h) * 8192 + wv * 1024 + 0]);   \
    GLD16(gB + (size_t)((h) * 128 + 8) * DIN + (kb), &sB[b][(h) * 8192 + wv * 1024 + 512]); \
} while (0)

#define RD_AF0(b) do { _Pragma("unroll") \
    for (int mi = 0; mi < 4; ++mi) { \
        af0[mi][0] = *(const bf16x8*)&sA[b][aRow + mi * 1024 + ko0]; \
        af0[mi][1] = *(const bf16x8*)&sA[b][aRow + mi * 1024 + ko1]; } } while (0)
#define RD_AF1(b) do { _Pragma("unroll") \
    for (int mi = 0; mi < 4; ++mi) { \
        af1[mi][0] = *(const bf16x8*)&sA[b][aRow + (4 + mi) * 1024 + ko0]; \
        af1[mi][1] = *(const bf16x8*)&sA[b][aRow + (4 + mi) * 1024 + ko1]; } } while (0)
#define RD_BF0(b) do { _Pragma("unroll") \
    for (int ni = 0; ni < 2; ++ni) { \
        bf0[ni][0] = *(const bf16x8*)&sB[b][bRow + ni * 1024 + ko0]; \
        bf0[ni][1] = *(const bf16x8*)&sB[b][bRow + ni * 1024 + ko1]; } } while (0)
#define RD_BF1(b) do { _Pragma("unroll") \
    for (int ni = 0; ni < 2; ++ni) { \
        bf1[ni][0] = *(const bf16x8*)&sB[b][bRow + (2 + ni) * 1024 + ko0]; \
        bf1[ni][1] = *(const bf16x8*)&sB[b][bRow + (2 + ni) * 1024 + ko1]; } } while (0)

// 16 MFMAs: one C-quadrant (4m x 2n) over K=64 (2 chained kk-steps)
#define MM(afr, mbase, bfr, nbase) do { _Pragma("unroll") \
    for (int mi = 0; mi < 4; ++mi) { _Pragma("unroll") \
        for (int ni = 0; ni < 2; ++ni) { \
            acc[(mbase) + mi][(nbase) + ni] = __builtin_amdgcn_mfma_f32_16x16x32_bf16( \
                afr[mi][0], bfr[ni][0], acc[(mbase) + mi][(nbase) + ni], 0, 0, 0); \
            acc[(mbase) + mi][(nbase) + ni] = __builtin_amdgcn_mfma_f32_16x16x32_bf16( \
                afr[mi][1], bfr[ni][1], acc[(mbase) + mi][(nbase) + ni], 0, 0, 0); } } } while (0)

__global__ __launch_bounds__(512, 2)
void gemm_bt(const unsigned short* __restrict__ X,    // [MROWS][DIN] bf16 bits
             const unsigned short* __restrict__ Wt,   // [DOUT][DIN]  bf16 bits
             float* __restrict__ out) {               // [MROWS][DOUT] fp32
    __shared__ __align__(16) bf16_t sA[2][256 * 64];  // 64 KB
    __shared__ __align__(16) bf16_t sB[2][256 * 64];  // 64 KB

    const int tid  = threadIdx.x;
    const int lane = tid & 63;
    const int wv   = tid >> 6;        // 0..7
    const int wm   = wv >> 2;         // 0..1  (wave tile 128x64)
    const int wn   = wv & 3;          // 0..3

    // bijective XCD swizzle (512 % 8 == 0): XCD x gets contiguous wg chunk
    const int bid = blockIdx.x;
    const int wg  = (bid & 7) * 64 + (bid >> 3);
    const int bm  = wg & 31;          // fast over M -> Wt panel stays hot
    const int bn  = wg >> 5;          // 0..15

    // ---- staging source addresses (pre-swizzled global chunk)
    const int r8   = lane >> 3;
    const int kcol = ((lane & 7) ^ r8) * 8;
    const unsigned short* gA = X  + (size_t)(bm * 256 + wv * 16 + r8) * DIN + kcol;
    const unsigned short* gB = Wt + (size_t)(bn * 256 + wv * 16 + r8) * DIN + kcol;

    // ---- fragment read offsets (row&7 == lane&7 -> unswizzle with lane&7)
    const int l15  = lane & 15;
    const int l7   = lane & 7;
    const int aRow = (wm * 128 + l15) * 64;
    const int bRow = (wn * 64 + l15) * 64;
    const int ko0  = (((lane >> 4) + 0) ^ l7) * 8;   // kk-step 0
    const int ko1  = (((lane >> 4) + 4) ^ l7) * 8;   // kk-step 1

    bf16x8 af0[4][2], af1[4][2], bf0[2][2], bf1[2][2];
    f32x4 acc[8][4];
#pragma unroll
    for (int i = 0; i < 8; ++i)
#pragma unroll
        for (int j = 0; j < 4; ++j) acc[i][j] = (f32x4){0.f, 0.f, 0.f, 0.f};

    // ---- prologue: buf0 <- Ktile0 (4 halves), buf1.A <- Ktile1 (2 halves)
    STG_A(0, 0, 0); STG_A(0, 1, 0);
    STG_B(0, 0, 0); STG_B(0, 1, 0);
    STG_A(1, 0, 64); STG_A(1, 1, 64);
    asm volatile("s_waitcnt vmcnt(4)" ::: "memory");   // buf0 landed, buf1.A in flight
    __builtin_amdgcn_s_barrier();
    SB;

#pragma unroll 1
    for (int it = 0; it < DIN / 128; ++it) {
        const int kB1 = it * 128 + 64;                 // Ktile 2i+1 (B halves)
        const int k0  = (it * 128 + 128) & (DIN - 1);  // Ktile 2i+2 (wraps: dead data)
        const int kA1 = (it * 128 + 192) & (DIN - 1);  // Ktile 2i+3 (wraps: dead data)

        // -------- K-tile 2i from buf0 --------
        // P1: af0,bf0 (12 reads); stage buf1.B0
        RD_AF0(0); RD_BF0(0); STG_B(1, 0, kB1);
        asm volatile("s_waitcnt lgkmcnt(8)" ::: "memory");
        PH_HEAD; MM(af0, 0, bf0, 0); PH_TAIL;
        // P2: af1 (8 reads); stage buf1.B1
        RD_AF1(0); STG_B(1, 1, kB1);
        PH_HEAD; MM(af1, 4, bf0, 0); PH_TAIL;
        // P3: bf1 (4 reads); stage buf0.A0 (A(buf0) reads done at P2)
        RD_BF1(0); STG_A(0, 0, k0);
        PH_HEAD; MM(af1, 4, bf1, 2); PH_TAIL;
        // P4: no reads; stage buf0.A1; counted vmcnt -> buf1 ready
        STG_A(0, 1, k0);
        PH_HEAD; MM(af0, 0, bf1, 2); PH_TAIL_VM;

        // -------- K-tile 2i+1 from buf1 --------
        // P5: af0,bf0; stage buf0.B0 (B(buf0) reads done at P3)
        RD_AF0(1); RD_BF0(1); STG_B(0, 0, k0);
        asm volatile("s_waitcnt lgkmcnt(8)" ::: "memory");
        PH_HEAD; MM(af0, 0, bf0, 0); PH_TAIL;
        // P6: af1; stage buf0.B1
        RD_AF1(1); STG_B(0, 1, k0);
        PH_HEAD; MM(af1, 4, bf0, 0); PH_TAIL;
        // P7: bf1; stage buf1.A0 (A(buf1) reads done at P6)
        RD_BF1(1); STG_A(1, 0, kA1);
        PH_HEAD; MM(af1, 4, bf1, 2); PH_TAIL;
        // P8: no reads; stage buf1.A1; counted vmcnt -> buf0 ready
        STG_A(1, 1, kA1);
        PH_HEAD; MM(af0, 0, bf1, 2); PH_TAIL_VM;
    }

    // ---- epilogue: D row = (lane>>4)*4 + r, col = lane&15
    const int crow0 = bm * 256 + wm * 128 + (lane >> 4) * 4;
    const int ccol0 = bn * 256 + wn * 64 + l15;
#pragma unroll
    for (int mi = 0; mi < 8; ++mi)
#pragma unroll
        for (int ni = 0; ni < 4; ++ni)
#pragma unroll
            for (int r = 0; r < 4; ++r)
                out[(size_t)(crow0 + mi * 16 + r) * DOUT + (ccol0 + ni * 16)] =
                    acc[mi][ni][r];
}

extern "C" void kernel_launch(void* const* d_in, const int* in_sizes, int n_in,
                              void* d_out, int out_size, void* d_ws, size_t ws_size,
                              hipStream_t stream) {
    const float* x     = (const float*)d_in[0];
    const float* baseT = (const float*)d_in[1];
    const int*   mask  = (const int*)d_in[2];
    const float* coeff = (const float*)d_in[3];

    unsigned short* Wt = (unsigned short*)d_ws;                                   // 32 MB
    unsigned short* Xb = (unsigned short*)((char*)d_ws + (size_t)DIN * DOUT * 2); // 64 MB
    float* out = (float*)d_out;

    build_wt<<<dim3(DOUT / 64, DIN / 64), 256, 0, stream>>>(baseT, mask, coeff, Wt);

    cvt_x<<<(MROWS * DIN / 16) / 256, 256, 0, stream>>>(x, Xb);

    gemm_bt<<<(MROWS / 256) * (DOUT / 256), 512, 0, stream>>>(Xb, Wt, out);
}

// Round 3
// 599.961 us; speedup vs baseline: 1.0024x; 1.0024x over previous
//
#include <hip/hip_runtime.h>
#include <hip/hip_bf16.h>
#include <stdint.h>

#define DIN   4096
#define DOUT  4096
#define MROWS 8192   // B*S = 4*2048

typedef __bf16 bf16_t;
typedef __attribute__((ext_vector_type(8))) __bf16 bf16x8;
typedef __attribute__((ext_vector_type(4))) float   f32x4;

__device__ __forceinline__ unsigned short f2bf(float f) {
    union { float f; unsigned u; } v; v.f = f;
    unsigned r = v.u + 0x7FFFu + ((v.u >> 16) & 1u);   // RNE
    return (unsigned short)(r >> 16);
}

// ---------------------------------------------------------------------------
// Kernel 1: Wt[n][k] = bf16( base_T[k][n] + c * (2*mask[k][n] - 1) )
// ---------------------------------------------------------------------------
__global__ __launch_bounds__(256)
void build_wt(const float* __restrict__ baseT,
              const int*   __restrict__ mask,
              const float* __restrict__ coeff,
              unsigned short* __restrict__ Wt) {
    __shared__ float tile[64][68];
    const float c = coeff[0];
    const int t  = threadIdx.x;
    const int n0 = blockIdx.x * 64;
    const int k0 = blockIdx.y * 64;

    const int kr = t >> 4;
    const int nv = (t & 15) * 4;
#pragma unroll
    for (int i = 0; i < 4; ++i) {
        const int kl = i * 16 + kr;
        const size_t idx = (size_t)(k0 + kl) * DOUT + n0 + nv;
        float4 b4 = *(const float4*)(baseT + idx);
        int4   m4 = *(const int4*)(mask + idx);
        float4 v;
        v.x = b4.x + c * (float)(2 * m4.x - 1);
        v.y = b4.y + c * (float)(2 * m4.y - 1);
        v.z = b4.z + c * (float)(2 * m4.z - 1);
        v.w = b4.w + c * (float)(2 * m4.w - 1);
        *(float4*)&tile[kl][nv] = v;
    }
    __syncthreads();

    const int nr = t >> 4;
    const int kv = (t & 15) * 4;
#pragma unroll
    for (int j = 0; j < 4; ++j) {
        const int nl = j * 16 + nr;
        ushort4 o;
        o.x = f2bf(tile[kv + 0][nl]);
        o.y = f2bf(tile[kv + 1][nl]);
        o.z = f2bf(tile[kv + 2][nl]);
        o.w = f2bf(tile[kv + 3][nl]);
        *(ushort4*)(Wt + (size_t)(n0 + nl) * DIN + k0 + kv) = o;
    }
}

// ---------------------------------------------------------------------------
// Kernel 2: x fp32 -> bf16 bits, 16 elem/thread
// ---------------------------------------------------------------------------
__global__ __launch_bounds__(256)
void cvt_x(const float* __restrict__ x, unsigned short* __restrict__ xb) {
    const int i = blockIdx.x * 256 + threadIdx.x;
    const float4* xv = (const float4*)x;
    float4 a = xv[4 * i + 0];
    float4 b = xv[4 * i + 1];
    float4 c = xv[4 * i + 2];
    float4 d = xv[4 * i + 3];
    union { ushort4 s[2]; uint4 u; } p0, p1;
    p0.s[0] = make_ushort4(f2bf(a.x), f2bf(a.y), f2bf(a.z), f2bf(a.w));
    p0.s[1] = make_ushort4(f2bf(b.x), f2bf(b.y), f2bf(b.z), f2bf(b.w));
    p1.s[0] = make_ushort4(f2bf(c.x), f2bf(c.y), f2bf(c.z), f2bf(c.w));
    p1.s[1] = make_ushort4(f2bf(d.x), f2bf(d.y), f2bf(d.z), f2bf(d.w));
    uint4* ov = (uint4*)xb;
    ov[2 * i + 0] = p0.u;
    ov[2 * i + 1] = p1.u;
}

// ---------------------------------------------------------------------------
// Kernel 3: out[m][n] = sum_k X[m][k] * Wt[n][k]   (bf16 in, fp32 out)
// 256x256 tile, BK=64, 8 waves (2Mx4N), 8-phase counted-vmcnt schedule
// (T2+T3+T4+T5 per guide §5). 2 K-tiles per loop iteration, double-buffered
// 128 KiB LDS. vmcnt(4) only at phases 4/8 -> loads stay in flight across
// barriers (no vmcnt(0) drain in the main loop).
// NO sched_barrier(0) anywhere: ds_reads are IR-level loads (compiler tracks
// MFMA deps and inserts its own waits); fresh-buffer reads (P1/P5) cannot
// hoist past the preceding vmcnt asm ("memory" clobber). m141 measured SB
// order-pinning at -42% -- this is the round-1 defect being removed.
// LDS swizzle: phys chunk p at row r holds global chunk p ^ (r&7)
// (pre-swizzled global source; linear global_load_lds dest) -> conflict-free
// ds_read_b128 fragments (2-way = free).
// Stage->phase map (iter i; Ktiles 2i in buf0, 2i+1 in buf1):
//   P1: buf1.B0@(2i+1)  P2: buf1.B1@(2i+1)   [B(buf1) reads ended prev P6]
//   P3: buf0.A0@(2i+2)  P4: buf0.A1@(2i+2)   [A(buf0) reads ended P2]
//   P5: buf0.B0@(2i+2)  P6: buf0.B1@(2i+2)   [B(buf0) reads ended P3]
//   P7: buf1.A0@(2i+3)  P8: buf1.A1@(2i+3)   [A(buf1) reads ended P6]
// vmcnt(4)@P4 -> stages through P2 landed (buf1 complete for P5 reads);
// vmcnt(4)@P8 -> stages through P6 landed (buf0 complete for P1' reads).
// ---------------------------------------------------------------------------
#define AS1 __attribute__((address_space(1)))
#define AS3 __attribute__((address_space(3)))
#define GLD16(src, dst) \
    __builtin_amdgcn_global_load_lds((const AS1 void*)(src), (AS3 void*)(dst), 16, 0, 0)

#define PH_HEAD do { __builtin_amdgcn_s_barrier(); \
    asm volatile("s_waitcnt lgkmcnt(0)" ::: "memory"); \
    __builtin_amdgcn_s_setprio(1); } while (0)
#define PH_TAIL do { __builtin_amdgcn_s_setprio(0); \
    __builtin_amdgcn_s_barrier(); } while (0)
#define PH_TAIL_VM do { __builtin_amdgcn_s_setprio(0); \
    asm volatile("s_waitcnt vmcnt(4)" ::: "memory"); \
    __builtin_amdgcn_s_barrier(); } while (0)

// stage one 128-row half-tile: wave wv instr j covers rows wv*16+j*8..+8,
// lane l -> row +(l>>3), phys chunk l&7 <- global chunk (l&7)^(l>>3)
#define STG_A(b, h, kb) do { \
    GLD16(gA + (size_t)((h) * 128 + 0) * DIN + (kb), &sA[b][(h) * 8192 + wv * 1024 + 0]);   \
    GLD16(gA + (size_t)((h) * 128 + 8) * DIN + (kb), &sA[b][(h) * 8192 + wv * 1024 + 512]); \
} while (0)
#define STG_B(b, h, kb) do { \
    GLD16(gB + (size_t)((h) * 128 + 0) * DIN + (kb), &sB[b][(h) * 8192 + wv * 1024 + 0]);   \
    GLD16(gB + (size_t)((h) * 128 + 8) * DIN + (kb), &sB[b][(h) * 8192 + wv * 1024 + 512]); \
} while (0)

#define RD_AF0(b) do { _Pragma("unroll") \
    for (int mi = 0; mi < 4; ++mi) { \
        af0[mi][0] = *(const bf16x8*)&sA[b][aRow + mi * 1024 + ko0]; \
        af0[mi][1] = *(const bf16x8*)&sA[b][aRow + mi * 1024 + ko1]; } } while (0)
#define RD_AF1(b) do { _Pragma("unroll") \
    for (int mi = 0; mi < 4; ++mi) { \
        af1[mi][0] = *(const bf16x8*)&sA[b][aRow + (4 + mi) * 1024 + ko0]; \
        af1[mi][1] = *(const bf16x8*)&sA[b][aRow + (4 + mi) * 1024 + ko1]; } } while (0)
#define RD_BF0(b) do { _Pragma("unroll") \
    for (int ni = 0; ni < 2; ++ni) { \
        bf0[ni][0] = *(const bf16x8*)&sB[b][bRow + ni * 1024 + ko0]; \
        bf0[ni][1] = *(const bf16x8*)&sB[b][bRow + ni * 1024 + ko1]; } } while (0)
#define RD_BF1(b) do { _Pragma("unroll") \
    for (int ni = 0; ni < 2; ++ni) { \
        bf1[ni][0] = *(const bf16x8*)&sB[b][bRow + (2 + ni) * 1024 + ko0]; \
        bf1[ni][1] = *(const bf16x8*)&sB[b][bRow + (2 + ni) * 1024 + ko1]; } } while (0)

// 16 MFMAs: one C-quadrant (4m x 2n) over K=64 (2 chained kk-steps)
#define MM(afr, mbase, bfr, nbase) do { _Pragma("unroll") \
    for (int mi = 0; mi < 4; ++mi) { _Pragma("unroll") \
        for (int ni = 0; ni < 2; ++ni) { \
            acc[(mbase) + mi][(nbase) + ni] = __builtin_amdgcn_mfma_f32_16x16x32_bf16( \
                afr[mi][0], bfr[ni][0], acc[(mbase) + mi][(nbase) + ni], 0, 0, 0); \
            acc[(mbase) + mi][(nbase) + ni] = __builtin_amdgcn_mfma_f32_16x16x32_bf16( \
                afr[mi][1], bfr[ni][1], acc[(mbase) + mi][(nbase) + ni], 0, 0, 0); } } } while (0)

__global__ __launch_bounds__(512, 2)
void gemm_bt(const unsigned short* __restrict__ X,    // [MROWS][DIN] bf16 bits
             const unsigned short* __restrict__ Wt,   // [DOUT][DIN]  bf16 bits
             float* __restrict__ out) {               // [MROWS][DOUT] fp32
    __shared__ __align__(16) bf16_t sA[2][256 * 64];  // 64 KB
    __shared__ __align__(16) bf16_t sB[2][256 * 64];  // 64 KB

    const int tid  = threadIdx.x;
    const int lane = tid & 63;
    const int wv   = tid >> 6;        // 0..7
    const int wm   = wv >> 2;         // 0..1  (wave tile 128x64)
    const int wn   = wv & 3;          // 0..3

    // bijective XCD swizzle (512 % 8 == 0): XCD x gets contiguous wg chunk
    const int bid = blockIdx.x;
    const int wg  = (bid & 7) * 64 + (bid >> 3);
    const int bm  = wg & 31;          // fast over M -> Wt panel stays hot in XCD L2
    const int bn  = wg >> 5;          // 0..15

    // ---- staging source addresses (pre-swizzled global chunk)
    const int r8   = lane >> 3;
    const int kcol = ((lane & 7) ^ r8) * 8;
    const unsigned short* gA = X  + (size_t)(bm * 256 + wv * 16 + r8) * DIN + kcol;
    const unsigned short* gB = Wt + (size_t)(bn * 256 + wv * 16 + r8) * DIN + kcol;

    // ---- fragment read offsets (row&7 == lane&7 -> unswizzle with lane&7)
    const int l15  = lane & 15;
    const int l7   = lane & 7;
    const int aRow = (wm * 128 + l15) * 64;
    const int bRow = (wn * 64 + l15) * 64;
    const int ko0  = (((lane >> 4) + 0) ^ l7) * 8;   // kk-step 0
    const int ko1  = (((lane >> 4) + 4) ^ l7) * 8;   // kk-step 1

    bf16x8 af0[4][2], af1[4][2], bf0[2][2], bf1[2][2];
    f32x4 acc[8][4];
#pragma unroll
    for (int i = 0; i < 8; ++i)
#pragma unroll
        for (int j = 0; j < 4; ++j) acc[i][j] = (f32x4){0.f, 0.f, 0.f, 0.f};

    // ---- prologue: buf0 <- Ktile0 (4 halves), buf1.A <- Ktile1 (2 halves)
    STG_A(0, 0, 0); STG_A(0, 1, 0);
    STG_B(0, 0, 0); STG_B(0, 1, 0);
    STG_A(1, 0, 64); STG_A(1, 1, 64);
    asm volatile("s_waitcnt vmcnt(4)" ::: "memory");   // buf0 landed, buf1.A in flight
    __builtin_amdgcn_s_barrier();

#pragma unroll 1
    for (int it = 0; it < DIN / 128; ++it) {
        const int kB1 = it * 128 + 64;                 // Ktile 2i+1 (B halves)
        const int k0  = (it * 128 + 128) & (DIN - 1);  // Ktile 2i+2 (wraps: dead data)
        const int kA1 = (it * 128 + 192) & (DIN - 1);  // Ktile 2i+3 (wraps: dead data)

        // -------- K-tile 2i from buf0 --------
        // P1: af0,bf0 (12 reads); stage buf1.B0
        RD_AF0(0); RD_BF0(0); STG_B(1, 0, kB1);
        asm volatile("s_waitcnt lgkmcnt(8)" ::: "memory");
        PH_HEAD; MM(af0, 0, bf0, 0); PH_TAIL;
        // P2: af1 (8 reads); stage buf1.B1
        RD_AF1(0); STG_B(1, 1, kB1);
        PH_HEAD; MM(af1, 4, bf0, 0); PH_TAIL;
        // P3: bf1 (4 reads); stage buf0.A0 (A(buf0) reads done at P2)
        RD_BF1(0); STG_A(0, 0, k0);
        PH_HEAD; MM(af1, 4, bf1, 2); PH_TAIL;
        // P4: no reads; stage buf0.A1; counted vmcnt -> buf1 ready
        STG_A(0, 1, k0);
        PH_HEAD; MM(af0, 0, bf1, 2); PH_TAIL_VM;

        // -------- K-tile 2i+1 from buf1 --------
        // P5: af0,bf0; stage buf0.B0 (B(buf0) reads done at P3)
        RD_AF0(1); RD_BF0(1); STG_B(0, 0, k0);
        asm volatile("s_waitcnt lgkmcnt(8)" ::: "memory");
        PH_HEAD; MM(af0, 0, bf0, 0); PH_TAIL;
        // P6: af1; stage buf0.B1
        RD_AF1(1); STG_B(0, 1, k0);
        PH_HEAD; MM(af1, 4, bf0, 0); PH_TAIL;
        // P7: bf1; stage buf1.A0 (A(buf1) reads done at P6)
        RD_BF1(1); STG_A(1, 0, kA1);
        PH_HEAD; MM(af1, 4, bf1, 2); PH_TAIL;
        // P8: no reads; stage buf1.A1; counted vmcnt -> buf0 ready
        STG_A(1, 1, kA1);
        PH_HEAD; MM(af0, 0, bf1, 2); PH_TAIL_VM;
    }

    // ---- epilogue: D row = (lane>>4)*4 + r, col = lane&15
    const int crow0 = bm * 256 + wm * 128 + (lane >> 4) * 4;
    const int ccol0 = bn * 256 + wn * 64 + l15;
#pragma unroll
    for (int mi = 0; mi < 8; ++mi)
#pragma unroll
        for (int ni = 0; ni < 4; ++ni)
#pragma unroll
            for (int r = 0; r < 4; ++r)
                out[(size_t)(crow0 + mi * 16 + r) * DOUT + (ccol0 + ni * 16)] =
                    acc[mi][ni][r];
}

extern "C" void kernel_launch(void* const* d_in, const int* in_sizes, int n_in,
                              void* d_out, int out_size, void* d_ws, size_t ws_size,
                              hipStream_t stream) {
    const float* x     = (const float*)d_in[0];
    const float* baseT = (const float*)d_in[1];
    const int*   mask  = (const int*)d_in[2];
    const float* coeff = (const float*)d_in[3];

    unsigned short* Wt = (unsigned short*)d_ws;                                   // 32 MB
    unsigned short* Xb = (unsigned short*)((char*)d_ws + (size_t)DIN * DOUT * 2); // 64 MB
    float* out = (float*)d_out;

    build_wt<<<dim3(DOUT / 64, DIN / 64), 256, 0, stream>>>(baseT, mask, coeff, Wt);

    cvt_x<<<(MROWS * DIN / 16) / 256, 256, 0, stream>>>(x, Xb);

    gemm_bt<<<(MROWS / 256) * (DOUT / 256), 512, 0, stream>>>(Xb, Wt, out);
}

// Round 4
// 586.049 us; speedup vs baseline: 1.0262x; 1.0237x over previous
//
#include <hip/hip_runtime.h>
#include <hip/hip_bf16.h>
#include <stdint.h>

#define DIN   4096
#define DOUT  4096
#define MROWS 8192   // B*S = 4*2048

typedef __bf16 bf16_t;
typedef __attribute__((ext_vector_type(8))) __bf16 bf16x8;
typedef __attribute__((ext_vector_type(4))) float   f32x4;

__device__ __forceinline__ unsigned short f2bf(float f) {
    union { float f; unsigned u; } v; v.f = f;
    unsigned r = v.u + 0x7FFFu + ((v.u >> 16) & 1u);   // RNE
    return (unsigned short)(r >> 16);
}

// ---------------------------------------------------------------------------
// Kernel 1 (fused prep):
//   blocks [0, 4096):      Wt[n][k] = bf16( base_T[k][n] + c*(2*mask[k][n]-1) )
//   blocks [4096, 12288):  Xb = bf16(x), 16 elem/thread
// Fused so prep cost shows as ONE dispatch row and one launch/drain boundary.
// ---------------------------------------------------------------------------
__global__ __launch_bounds__(256)
void prep(const float* __restrict__ x,
          const float* __restrict__ baseT,
          const int*   __restrict__ mask,
          const float* __restrict__ coeff,
          unsigned short* __restrict__ Wt,
          unsigned short* __restrict__ xb) {
    __shared__ float tile[64][68];
    const int b = blockIdx.x;
    const int t = threadIdx.x;

    if (b < 4096) {
        // ---- build_wt part (64x64 transpose tile) ----
        const float c = coeff[0];
        const int n0 = (b & 63) * 64;
        const int k0 = (b >> 6) * 64;

        const int kr = t >> 4;
        const int nv = (t & 15) * 4;
#pragma unroll
        for (int i = 0; i < 4; ++i) {
            const int kl = i * 16 + kr;
            const size_t idx = (size_t)(k0 + kl) * DOUT + n0 + nv;
            float4 b4 = *(const float4*)(baseT + idx);
            int4   m4 = *(const int4*)(mask + idx);
            float4 v;
            v.x = b4.x + c * (float)(2 * m4.x - 1);
            v.y = b4.y + c * (float)(2 * m4.y - 1);
            v.z = b4.z + c * (float)(2 * m4.z - 1);
            v.w = b4.w + c * (float)(2 * m4.w - 1);
            *(float4*)&tile[kl][nv] = v;
        }
        __syncthreads();

        const int nr = t >> 4;
        const int kv = (t & 15) * 4;
#pragma unroll
        for (int j = 0; j < 4; ++j) {
            const int nl = j * 16 + nr;
            ushort4 o;
            o.x = f2bf(tile[kv + 0][nl]);
            o.y = f2bf(tile[kv + 1][nl]);
            o.z = f2bf(tile[kv + 2][nl]);
            o.w = f2bf(tile[kv + 3][nl]);
            *(ushort4*)(Wt + (size_t)(n0 + nl) * DIN + k0 + kv) = o;
        }
    } else {
        // ---- cvt_x part ----
        const int i = (b - 4096) * 256 + t;
        const float4* xv = (const float4*)x;
        float4 a = xv[4 * i + 0];
        float4 bb = xv[4 * i + 1];
        float4 cc = xv[4 * i + 2];
        float4 d = xv[4 * i + 3];
        union { ushort4 s[2]; uint4 u; } p0, p1;
        p0.s[0] = make_ushort4(f2bf(a.x), f2bf(a.y), f2bf(a.z), f2bf(a.w));
        p0.s[1] = make_ushort4(f2bf(bb.x), f2bf(bb.y), f2bf(bb.z), f2bf(bb.w));
        p1.s[0] = make_ushort4(f2bf(cc.x), f2bf(cc.y), f2bf(cc.z), f2bf(cc.w));
        p1.s[1] = make_ushort4(f2bf(d.x), f2bf(d.y), f2bf(d.z), f2bf(d.w));
        uint4* ov = (uint4*)xb;
        ov[2 * i + 0] = p0.u;
        ov[2 * i + 1] = p1.u;
    }
}

// ---------------------------------------------------------------------------
// Kernel 2: out[m][n] = sum_k X[m][k] * Wt[n][k]   (bf16 in, fp32 out)
// 256x256 tile, BK=64, 8 waves (2Mx4N), 8-phase counted-vmcnt schedule.
// v2 stage map: every load now has 4-5 phases of lead before its vmcnt wait
// (was 2 phases for B-halves -> twice-per-iter HBM-tail stall, the R3 37%
// MfmaUtil defect). Stages at earliest legal slots:
//   P3: buf0.A0   P4: buf0.{A1,B0,B1}   (sA[0] free after P2-tail, sB[0]
//   P7: buf1.A0   P8: buf1.{A1,B0,B1}    free after P3-tail; mirror for buf1)
// vmcnt(8) at P4-tail (drains buf1's 8 loads, issued prev P7/P8 = 4-5 phases
// earlier) and P8-tail (drains buf0's 8, issued P3/P4). Invariant: exactly 8
// loads (next buffer's full set) in flight after each wait.
// LDS swizzle: phys chunk p at row r holds global chunk p ^ (r&7) -> 
// conflict-free ds_read_b128 (verified: SQ_LDS_BANK_CONFLICT = 0).
// ---------------------------------------------------------------------------
#define AS1 __attribute__((address_space(1)))
#define AS3 __attribute__((address_space(3)))
#define GLD16(src, dst) \
    __builtin_amdgcn_global_load_lds((const AS1 void*)(src), (AS3 void*)(dst), 16, 0, 0)

#define PH_HEAD do { __builtin_amdgcn_s_barrier(); \
    asm volatile("s_waitcnt lgkmcnt(0)" ::: "memory"); \
    __builtin_amdgcn_s_setprio(1); } while (0)
#define PH_TAIL do { __builtin_amdgcn_s_setprio(0); \
    __builtin_amdgcn_s_barrier(); } while (0)
#define PH_TAIL_VM do { __builtin_amdgcn_s_setprio(0); \
    asm volatile("s_waitcnt vmcnt(8)" ::: "memory"); \
    __builtin_amdgcn_s_barrier(); } while (0)

// stage one 128-row half-tile: wave wv instr j covers rows wv*16+j*8..+8,
// lane l -> row +(l>>3), phys chunk l&7 <- global chunk (l&7)^(l>>3)
#define STG_A(b, h, kb) do { \
    GLD16(gA + (size_t)((h) * 128 + 0) * DIN + (kb), &sA[b][(h) * 8192 + wv * 1024 + 0]);   \
    GLD16(gA + (size_t)((h) * 128 + 8) * DIN + (kb), &sA[b][(h) * 8192 + wv * 1024 + 512]); \
} while (0)
#define STG_B(b, h, kb) do { \
    GLD16(gB + (size_t)((h) * 128 + 0) * DIN + (kb), &sB[b][(h) * 8192 + wv * 1024 + 0]);   \
    GLD16(gB + (size_t)((h) * 128 + 8) * DIN + (kb), &sB[b][(h) * 8192 + wv * 1024 + 512]); \
} while (0)

#define RD_AF0(b) do { _Pragma("unroll") \
    for (int mi = 0; mi < 4; ++mi) { \
        af0[mi][0] = *(const bf16x8*)&sA[b][aRow + mi * 1024 + ko0]; \
        af0[mi][1] = *(const bf16x8*)&sA[b][aRow + mi * 1024 + ko1]; } } while (0)
#define RD_AF1(b) do { _Pragma("unroll") \
    for (int mi = 0; mi < 4; ++mi) { \
        af1[mi][0] = *(const bf16x8*)&sA[b][aRow + (4 + mi) * 1024 + ko0]; \
        af1[mi][1] = *(const bf16x8*)&sA[b][aRow + (4 + mi) * 1024 + ko1]; } } while (0)
#define RD_BF0(b) do { _Pragma("unroll") \
    for (int ni = 0; ni < 2; ++ni) { \
        bf0[ni][0] = *(const bf16x8*)&sB[b][bRow + ni * 1024 + ko0]; \
        bf0[ni][1] = *(const bf16x8*)&sB[b][bRow + ni * 1024 + ko1]; } } while (0)
#define RD_BF1(b) do { _Pragma("unroll") \
    for (int ni = 0; ni < 2; ++ni) { \
        bf1[ni][0] = *(const bf16x8*)&sB[b][bRow + (2 + ni) * 1024 + ko0]; \
        bf1[ni][1] = *(const bf16x8*)&sB[b][bRow + (2 + ni) * 1024 + ko1]; } } while (0)

// 16 MFMAs: one C-quadrant (4m x 2n) over K=64 (2 chained kk-steps)
#define MM(afr, mbase, bfr, nbase) do { _Pragma("unroll") \
    for (int mi = 0; mi < 4; ++mi) { _Pragma("unroll") \
        for (int ni = 0; ni < 2; ++ni) { \
            acc[(mbase) + mi][(nbase) + ni] = __builtin_amdgcn_mfma_f32_16x16x32_bf16( \
                afr[mi][0], bfr[ni][0], acc[(mbase) + mi][(nbase) + ni], 0, 0, 0); \
            acc[(mbase) + mi][(nbase) + ni] = __builtin_amdgcn_mfma_f32_16x16x32_bf16( \
                afr[mi][1], bfr[ni][1], acc[(mbase) + mi][(nbase) + ni], 0, 0, 0); } } } while (0)

__global__ __launch_bounds__(512, 2)
void gemm_bt(const unsigned short* __restrict__ X,    // [MROWS][DIN] bf16 bits
             const unsigned short* __restrict__ Wt,   // [DOUT][DIN]  bf16 bits
             float* __restrict__ out) {               // [MROWS][DOUT] fp32
    __shared__ __align__(16) bf16_t sA[2][256 * 64];  // 64 KB
    __shared__ __align__(16) bf16_t sB[2][256 * 64];  // 64 KB

    const int tid  = threadIdx.x;
    const int lane = tid & 63;
    const int wv   = tid >> 6;        // 0..7
    const int wm   = wv >> 2;         // 0..1  (wave tile 128x64)
    const int wn   = wv & 3;          // 0..3

    // bijective XCD swizzle (512 % 8 == 0): XCD x gets contiguous wg chunk
    const int bid = blockIdx.x;
    const int wg  = (bid & 7) * 64 + (bid >> 3);
    const int bm  = wg & 31;          // fast over M -> Wt panel stays hot in XCD L2
    const int bn  = wg >> 5;          // 0..15

    // ---- staging source addresses (pre-swizzled global chunk)
    const int r8   = lane >> 3;
    const int kcol = ((lane & 7) ^ r8) * 8;
    const unsigned short* gA = X  + (size_t)(bm * 256 + wv * 16 + r8) * DIN + kcol;
    const unsigned short* gB = Wt + (size_t)(bn * 256 + wv * 16 + r8) * DIN + kcol;

    // ---- fragment read offsets (row&7 == lane&7 -> unswizzle with lane&7)
    const int l15  = lane & 15;
    const int l7   = lane & 7;
    const int aRow = (wm * 128 + l15) * 64;
    const int bRow = (wn * 64 + l15) * 64;
    const int ko0  = (((lane >> 4) + 0) ^ l7) * 8;   // kk-step 0
    const int ko1  = (((lane >> 4) + 4) ^ l7) * 8;   // kk-step 1

    bf16x8 af0[4][2], af1[4][2], bf0[2][2], bf1[2][2];
    f32x4 acc[8][4];
#pragma unroll
    for (int i = 0; i < 8; ++i)
#pragma unroll
        for (int j = 0; j < 4; ++j) acc[i][j] = (f32x4){0.f, 0.f, 0.f, 0.f};

    // ---- prologue: buf0 <- Ktile0 (8 loads), buf1 <- Ktile1 (8 loads)
    STG_A(0, 0, 0);  STG_A(0, 1, 0);
    STG_B(0, 0, 0);  STG_B(0, 1, 0);
    STG_A(1, 0, 64); STG_A(1, 1, 64);
    STG_B(1, 0, 64); STG_B(1, 1, 64);
    asm volatile("s_waitcnt vmcnt(8)" ::: "memory");   // buf0 landed; buf1's 8 in flight
    __builtin_amdgcn_s_barrier();

#pragma unroll 1
    for (int it = 0; it < DIN / 128; ++it) {
        const int k0  = (it * 128 + 128) & (DIN - 1);  // Ktile 2i+2 -> buf0 (wrap: dead)
        const int kA1 = (it * 128 + 192) & (DIN - 1);  // Ktile 2i+3 -> buf1 (wrap: dead)

        // -------- K-tile 2i from buf0 --------
        // P1: af0,bf0 (12 reads); no stage
        RD_AF0(0); RD_BF0(0);
        asm volatile("s_waitcnt lgkmcnt(8)" ::: "memory");
        PH_HEAD; MM(af0, 0, bf0, 0); PH_TAIL;
        // P2: af1 (8 reads); no stage
        RD_AF1(0);
        PH_HEAD; MM(af1, 4, bf0, 0); PH_TAIL;
        // P3: bf1 (4 reads); stage buf0.A0 (sA[0] reads ended P2-tail)
        RD_BF1(0); STG_A(0, 0, k0);
        PH_HEAD; MM(af1, 4, bf1, 2); PH_TAIL;
        // P4: stage buf0.{A1,B0,B1} (sB[0] reads ended P3-tail); wait buf1
        STG_A(0, 1, k0); STG_B(0, 0, k0); STG_B(0, 1, k0);
        PH_HEAD; MM(af0, 0, bf1, 2); PH_TAIL_VM;   // vmcnt(8): drains buf1's 8

        // -------- K-tile 2i+1 from buf1 --------
        // P5: af0,bf0 (12 reads); no stage
        RD_AF0(1); RD_BF0(1);
        asm volatile("s_waitcnt lgkmcnt(8)" ::: "memory");
        PH_HEAD; MM(af0, 0, bf0, 0); PH_TAIL;
        // P6: af1; no stage
        RD_AF1(1);
        PH_HEAD; MM(af1, 4, bf0, 0); PH_TAIL;
        // P7: bf1; stage buf1.A0 (sA[1] reads ended P6-tail)
        RD_BF1(1); STG_A(1, 0, kA1);
        PH_HEAD; MM(af1, 4, bf1, 2); PH_TAIL;
        // P8: stage buf1.{A1,B0,B1} (sB[1] reads ended P7-tail); wait buf0
        STG_A(1, 1, kA1); STG_B(1, 0, kA1); STG_B(1, 1, kA1);
        PH_HEAD; MM(af0, 0, bf1, 2); PH_TAIL_VM;   // vmcnt(8): drains buf0's 8
    }

    // ---- epilogue: D row = (lane>>4)*4 + r, col = lane&15
    const int crow0 = bm * 256 + wm * 128 + (lane >> 4) * 4;
    const int ccol0 = bn * 256 + wn * 64 + l15;
#pragma unroll
    for (int mi = 0; mi < 8; ++mi)
#pragma unroll
        for (int ni = 0; ni < 4; ++ni)
#pragma unroll
            for (int r = 0; r < 4; ++r)
                out[(size_t)(crow0 + mi * 16 + r) * DOUT + (ccol0 + ni * 16)] =
                    acc[mi][ni][r];
}

extern "C" void kernel_launch(void* const* d_in, const int* in_sizes, int n_in,
                              void* d_out, int out_size, void* d_ws, size_t ws_size,
                              hipStream_t stream) {
    const float* x     = (const float*)d_in[0];
    const float* baseT = (const float*)d_in[1];
    const int*   mask  = (const int*)d_in[2];
    const float* coeff = (const float*)d_in[3];

    unsigned short* Wt = (unsigned short*)d_ws;                                   // 32 MB
    unsigned short* Xb = (unsigned short*)((char*)d_ws + (size_t)DIN * DOUT * 2); // 64 MB
    float* out = (float*)d_out;

    prep<<<4096 + (MROWS * DIN / 16) / 256, 256, 0, stream>>>(x, baseT, mask, coeff, Wt, Xb);

    gemm_bt<<<(MROWS / 256) * (DOUT / 256), 512, 0, stream>>>(Xb, Wt, out);
}